// Round 4
// baseline (125.979 us; speedup 1.0000x reference)
//
#include <hip/hip_runtime.h>
#include <hip/hip_bf16.h>

typedef __attribute__((ext_vector_type(4))) float f32x4;
typedef __attribute__((ext_vector_type(8))) short bh8;

#define DEVI static __device__ __forceinline__

constexpr int Bn = 2, T = 2048, C = 1024, H = 16, HD = 64;
constexpr int BH = Bn * H;   // 32
constexpr int M  = Bn * T;   // 4096
// fold 1/sqrt(HD) and log2(e) into Q so softmax uses exp2
constexpr float QSC = 0.125f * 1.44269504088896f;

DEVI unsigned short f2bf(float f) {
  unsigned int u = __builtin_bit_cast(unsigned int, f);
  u += 0x7FFFu + ((u >> 16) & 1u);   // RTNE
  return (unsigned short)(u >> 16);
}

DEVI unsigned int cvtpk(float lo, float hi) {  // 2xf32 -> packed 2xbf16 (1 VALU op)
  unsigned int r;
  asm("v_cvt_pk_bf16_f32 %0, %1, %2" : "=v"(r) : "v"(lo), "v"(hi));
  return r;
}

DEVI void gload16(const void* g, void* l) {
  __builtin_amdgcn_global_load_lds((const __attribute__((address_space(1))) void*)g,
                                   (__attribute__((address_space(3))) void*)l,
                                   16, 0, 0);
}

__global__ __launch_bounds__(256) void cvt_bf16(const float* __restrict__ in,
                                                unsigned short* __restrict__ out,
                                                int n) {
  int i = (blockIdx.x * 256 + threadIdx.x) * 4;
  if (i < n) {
    const float4 v = *(const float4*)(in + i);
    ushort4 o;
    o.x = f2bf(v.x); o.y = f2bf(v.y); o.z = f2bf(v.z); o.w = f2bf(v.w);
    *(ushort4*)(out + i) = o;
  }
}

// C = A @ B^T (+bias). 128x128 tile, BK=64, 4 waves, 16x16x32 bf16 MFMA.
// EPI 0: fp32 out + bias. EPI 1: qkv scatter; V written kv-PERMUTED within each
// 128-tile (kappa bit-shuffle) so attn's P-fragment is lane-local (see attn).
template <int EPI>
__global__ __launch_bounds__(256) void gemm_bt(
    const unsigned short* __restrict__ A, const unsigned short* __restrict__ Bw,
    const float* __restrict__ bias, int N, int K,
    unsigned short* __restrict__ Qb, unsigned short* __restrict__ Kb,
    unsigned short* __restrict__ Vb, float* __restrict__ Outf) {
  __shared__ unsigned short As[128 * 64];
  __shared__ unsigned short Bs[128 * 64];

  const int tid  = threadIdx.x;
  const int lane = tid & 63;
  const int wid  = tid >> 6;
  const int wm = wid >> 1, wn = wid & 1;
  const int m0 = blockIdx.y * 128;
  const int n0 = blockIdx.x * 128;

  const int srow = lane >> 3;
  const int gp   = lane & 7;

  const unsigned short* Ab = A + (size_t)m0 * K;
  const unsigned short* Bb = Bw + (size_t)n0 * K;

  f32x4 acc[4][4] = {};

  for (int kt = 0; kt < K; kt += 64) {
    __syncthreads();
#pragma unroll
    for (int j = 0; j < 4; ++j) {
      const int row = wid * 32 + j * 8 + srow;
      const int gs  = gp ^ (row & 7);
      gload16(Ab + (size_t)row * K + kt + gs * 8, &As[(wid * 32 + j * 8) * 64]);
    }
#pragma unroll
    for (int j = 0; j < 4; ++j) {
      const int row = wid * 32 + j * 8 + srow;
      const int gs  = gp ^ (row & 7);
      gload16(Bb + (size_t)row * K + kt + gs * 8, &Bs[(wid * 32 + j * 8) * 64]);
    }
    __syncthreads();

#pragma unroll
    for (int kk = 0; kk < 2; ++kk) {
      bh8 af[4], bfr[4];
#pragma unroll
      for (int i = 0; i < 4; ++i) {
        const int row  = wm * 64 + i * 16 + (lane & 15);
        const int gran = kk * 4 + (lane >> 4);
        af[i] = *(const bh8*)&As[row * 64 + ((gran ^ (row & 7)) * 8)];
      }
#pragma unroll
      for (int j = 0; j < 4; ++j) {
        const int row  = wn * 64 + j * 16 + (lane & 15);
        const int gran = kk * 4 + (lane >> 4);
        bfr[j] = *(const bh8*)&Bs[row * 64 + ((gran ^ (row & 7)) * 8)];
      }
#pragma unroll
      for (int i = 0; i < 4; ++i)
#pragma unroll
        for (int j = 0; j < 4; ++j)
          acc[i][j] = __builtin_amdgcn_mfma_f32_16x16x32_bf16(af[i], bfr[j],
                                                              acc[i][j], 0, 0, 0);
    }
  }

  const int rbase = m0 + wm * 64 + ((lane >> 4) << 2);
  const int cbase = n0 + wn * 64 + (lane & 15);

  if (EPI == 0) {
#pragma unroll
    for (int j = 0; j < 4; ++j) {
      const int n = cbase + j * 16;
      const float bv = bias[n];
#pragma unroll
      for (int i = 0; i < 4; ++i)
#pragma unroll
        for (int r = 0; r < 4; ++r) {
          const int m = rbase + i * 16 + r;
          Outf[(size_t)m * N + n] = acc[i][j][r] + bv;
        }
    }
  } else {
#pragma unroll
    for (int j = 0; j < 4; ++j) {
      const int n = cbase + j * 16;
      const float bv = bias[n];
      const int part = n >> 10;      // 0:q 1:k 2:v
      const int nn = n & 1023;
      const int h = nn >> 6, d = nn & 63;
#pragma unroll
      for (int i = 0; i < 4; ++i)
#pragma unroll
        for (int r = 0; r < 4; ++r) {
          const int m = rbase + i * 16 + r;
          const int b = m >> 11, t = m & (T - 1);
          const int bh = b * H + h;
          const float val = acc[i][j][r] + bv;
          if (part == 0)
            Qb[((size_t)(bh * T + t)) * HD + d] = f2bf(val * QSC);
          else if (part == 1)
            Kb[((size_t)(bh * T + t)) * HD + d] = f2bf(val);
          else {
            // kv-permutation within 128-tile: kp=[kk2|b1|l4|r] -> kap=[kk2|l4|b1|r]
            const int kp  = t & 127;
            const int kap = (kp & ~31) | (((kp >> 2) & 3) << 3) |
                            (((kp >> 4) & 1) << 2) | (kp & 3);
            const int tp  = (t & ~127) | kap;
            Vb[((size_t)(bh * HD + d)) * T + tp] = f2bf(val);  // transposed+permuted
          }
        }
    }
  }
}

// ---------------------------------------------------------------------------
// Flash attention, causal. Grid: (8, BH). Block: 512 thr = 8 waves.
// Block processes q-tiles qa and 15-qa as two sequential passes (17 kv-tiles).
// SWAPPED QK^T: s[j] = mfma(K,Q) -> D[kv][q], q = lane&15 is lane-local:
// softmax reduce = 31 in-reg ops + 2 shuffles. P-fragment built IN REGISTER
// via v_cvt_pk_bf16_f32 (V kv-permuted at GEMM1 so register order == frag
// order). No P LDS. PV: o = mfma(V^T,P) -> O^T[d][q].
// ---------------------------------------------------------------------------
__global__ __launch_bounds__(512, 2) void attn(
    const unsigned short* __restrict__ Qb, const unsigned short* __restrict__ Kb,
    const unsigned short* __restrict__ Vb, unsigned short* __restrict__ Yb) {
  __shared__ unsigned short Ks[2][128 * 64];
  __shared__ unsigned short Vs[2][64 * 128];

  const int tid  = threadIdx.x;
  const int lane = tid & 63;
  const int wid  = tid >> 6;          // 0..7
  const int bh   = blockIdx.y;
  const int b = bh >> 4, h = bh & 15;
  const int qa = blockIdx.x;          // 0..7 ; paired tile = 15-qa
  const int na = qa + 1;              // kv-tiles in pass 0

  const int l4  = lane >> 4;          // 0..3
  const int l15 = lane & 15;

  const unsigned short* Kbh = Kb + (size_t)bh * T * HD;
  const unsigned short* Vbh = Vb + (size_t)bh * HD * T;

  // staging geometry
  const int krow0 = wid * 16;
  const int kr    = lane >> 3;
  const int kgp   = lane & 7;
  const int vrow0 = wid * 8;
  const int vr    = lane >> 4;
  const int vgp   = lane & 15;

  // Q fragments (B-operand): lane holds Q[q = base+l15][k = kk*32 + l4*8 ..]
  bh8 qk0, qk1;
  {
    const size_t qo = ((size_t)(bh * T + qa * 128 + wid * 16 + l15)) * HD + l4 * 8;
    qk0 = *(const bh8*)&Qb[qo];
    qk1 = *(const bh8*)&Qb[qo + 32];
  }

  f32x4 o[4] = {};
  float mcur = -1e30f, lsum = 0.f;

  // prologue: stage tile 0 into buffer 0
#pragma unroll
  for (int sl = 0; sl < 2; ++sl) {
    const int row = krow0 + sl * 8 + kr;
    gload16(Kbh + (size_t)row * HD + ((kgp ^ (row & 7)) * 8), &Ks[0][(krow0 + sl * 8) * 64]);
  }
#pragma unroll
  for (int sl = 0; sl < 2; ++sl) {
    const int row = vrow0 + sl * 4 + vr;
    gload16(Vbh + (size_t)row * T + ((vgp ^ (row & 15)) * 8), &Vs[0][(vrow0 + sl * 4) * 128]);
  }
  __syncthreads();

  int cur = 0;
  for (int it = 0; it < 17; ++it) {
    // ---- prefetch next tile into the other buffer ----
    if (it < 16) {
      const int nit = it + 1;
      const int nkt = (nit < na ? nit : nit - na) * 128;
#pragma unroll
      for (int sl = 0; sl < 2; ++sl) {
        const int row = krow0 + sl * 8 + kr;
        gload16(Kbh + (size_t)(nkt + row) * HD + ((kgp ^ (row & 7)) * 8),
                &Ks[cur ^ 1][(krow0 + sl * 8) * 64]);
      }
#pragma unroll
      for (int sl = 0; sl < 2; ++sl) {
        const int row = vrow0 + sl * 4 + vr;
        gload16(Vbh + (size_t)row * T + nkt + ((vgp ^ (row & 15)) * 8),
                &Vs[cur ^ 1][(vrow0 + sl * 4) * 128]);
      }
    }

    // ---- pass boundary: flush pass-0 output, reinit state ----
    if (it == na) {
      const float inv = 1.f / lsum;
      const int t = qa * 128 + wid * 16 + l15;
#pragma unroll
      for (int dj = 0; dj < 4; ++dj) {
        ushort4 hw;
        hw.x = f2bf(o[dj][0] * inv); hw.y = f2bf(o[dj][1] * inv);
        hw.z = f2bf(o[dj][2] * inv); hw.w = f2bf(o[dj][3] * inv);
        *(ushort4*)&Yb[((size_t)(b * T + t)) * C + h * HD + dj * 16 + l4 * 4] = hw;
      }
      mcur = -1e30f; lsum = 0.f;
#pragma unroll
      for (int dj = 0; dj < 4; ++dj) o[dj] = f32x4{0.f, 0.f, 0.f, 0.f};
      const size_t qo = ((size_t)(bh * T + (15 - qa) * 128 + wid * 16 + l15)) * HD + l4 * 8;
      qk0 = *(const bh8*)&Qb[qo];
      qk1 = *(const bh8*)&Qb[qo + 32];
    }

    const int qt   = (it < na) ? qa : 15 - qa;
    const int kt   = (it < na ? it : it - na) * 128;
    const bool diag = (kt == qt * 128);

    // ---- S^T = K Q^T : lane holds s[j][r] = S[kv = kt+j*16+l4*4+r][q] ----
    f32x4 s[8] = {};
#pragma unroll
    for (int kk = 0; kk < 2; ++kk) {
      bh8 kfr[8];
#pragma unroll
      for (int j = 0; j < 8; ++j) {
        const int row  = j * 16 + l15;
        const int gran = kk * 4 + l4;
        kfr[j] = *(const bh8*)&Ks[cur][row * 64 + ((gran ^ (row & 7)) * 8)];
      }
      const bh8 qf = kk ? qk1 : qk0;
      __builtin_amdgcn_s_setprio(1);
#pragma unroll
      for (int j = 0; j < 8; ++j)
        s[j] = __builtin_amdgcn_mfma_f32_16x16x32_bf16(kfr[j], qf, s[j], 0, 0, 0);
      __builtin_amdgcn_s_setprio(0);
    }

    // ---- causal mask (diagonal tile only) ----
    if (diag) {
      const int qoff = wid * 16 + l15;
#pragma unroll
      for (int j = 0; j < 8; ++j)
#pragma unroll
        for (int r = 0; r < 4; ++r) {
          const int kvoff = j * 16 + l4 * 4 + r;
          if (kvoff > qoff) s[j][r] = -1e30f;
        }
    }

    // ---- online softmax: per-lane row, 2 shuffles per reduce ----
    float mx = fmaxf(fmaxf(s[0][0], s[0][1]), fmaxf(s[0][2], s[0][3]));
#pragma unroll
    for (int j = 1; j < 8; ++j)
      mx = fmaxf(mx, fmaxf(fmaxf(s[j][0], s[j][1]), fmaxf(s[j][2], s[j][3])));
    mx = fmaxf(mx, __shfl_xor(mx, 16));
    mx = fmaxf(mx, __shfl_xor(mx, 32));
    if (__any(mx > mcur + 8.f)) {          // defer-max (T13)
      const float mnew  = fmaxf(mcur, mx);
      const float alpha = exp2f(mcur - mnew);
      mcur = mnew; lsum *= alpha;
#pragma unroll
      for (int dj = 0; dj < 4; ++dj) o[dj] *= alpha;
    }
    float ps = 0.f;
#pragma unroll
    for (int j = 0; j < 8; ++j)
#pragma unroll
      for (int r = 0; r < 4; ++r) {
        const float p = exp2f(s[j][r] - mcur);
        s[j][r] = p;
        ps += p;
      }
    ps += __shfl_xor(ps, 16);
    ps += __shfl_xor(ps, 32);
    lsum += ps;

    // ---- O^T += V^T P : P-fragment packed in-register (V kv-permuted) ----
#pragma unroll
    for (int kk2 = 0; kk2 < 4; ++kk2) {
      const int gran = kk2 * 4 + l4;
      bh8 vf[4];
#pragma unroll
      for (int dj = 0; dj < 4; ++dj) {
        const int row = dj * 16 + l15;
        vf[dj] = *(const bh8*)&Vs[cur][row * 128 + ((gran ^ (row & 15)) * 8)];
      }
      int4 pw;
      pw.x = cvtpk(s[2 * kk2][0], s[2 * kk2][1]);
      pw.y = cvtpk(s[2 * kk2][2], s[2 * kk2][3]);
      pw.z = cvtpk(s[2 * kk2 + 1][0], s[2 * kk2 + 1][1]);
      pw.w = cvtpk(s[2 * kk2 + 1][2], s[2 * kk2 + 1][3]);
      const bh8 pf = __builtin_bit_cast(bh8, pw);
      __builtin_amdgcn_s_setprio(1);
#pragma unroll
      for (int dj = 0; dj < 4; ++dj)
        o[dj] = __builtin_amdgcn_mfma_f32_16x16x32_bf16(vf[dj], pf, o[dj], 0, 0, 0);
      __builtin_amdgcn_s_setprio(0);
    }

    __syncthreads();   // drains vmcnt(0): prefetched tile ready; buffer reuse safe
    cur ^= 1;
  }

  // ---- flush pass-1 output ----
  {
    const float inv = 1.f / lsum;
    const int t = (15 - qa) * 128 + wid * 16 + l15;
#pragma unroll
    for (int dj = 0; dj < 4; ++dj) {
      ushort4 hw;
      hw.x = f2bf(o[dj][0] * inv); hw.y = f2bf(o[dj][1] * inv);
      hw.z = f2bf(o[dj][2] * inv); hw.w = f2bf(o[dj][3] * inv);
      *(ushort4*)&Yb[((size_t)(b * T + t)) * C + h * HD + dj * 16 + l4 * 4] = hw;
    }
  }
}

extern "C" void kernel_launch(void* const* d_in, const int* in_sizes, int n_in,
                              void* d_out, int out_size, void* d_ws, size_t ws_size,
                              hipStream_t stream) {
  const float* x      = (const float*)d_in[0];
  const float* w_attn = (const float*)d_in[1];
  const float* b_attn = (const float*)d_in[2];
  const float* w_proj = (const float*)d_in[3];
  const float* b_proj = (const float*)d_in[4];
  float* out = (float*)d_out;

  unsigned short* xb  = (unsigned short*)d_ws;
  unsigned short* wab = xb  + (size_t)M * C;       // w_attn bf16 [3C][C]
  unsigned short* wpb = wab + (size_t)3 * C * C;   // w_proj bf16 [C][C]
  unsigned short* Qb  = wpb + (size_t)C * C;       // [BH][T][HD] (pre-scaled)
  unsigned short* Kb  = Qb  + (size_t)M * C;       // [BH][T][HD]
  unsigned short* Vb  = Kb  + (size_t)M * C;       // [BH][HD][T] transposed+permuted
  unsigned short* Yb  = xb;                        // alias: xb dead after GEMM1

  cvt_bf16<<<dim3((M * C) / 1024), 256, 0, stream>>>(x, xb, M * C);
  cvt_bf16<<<dim3((3 * C * C) / 1024), 256, 0, stream>>>(w_attn, wab, 3 * C * C);
  cvt_bf16<<<dim3((C * C) / 1024), 256, 0, stream>>>(w_proj, wpb, C * C);

  gemm_bt<1><<<dim3(3 * C / 128, M / 128), 256, 0, stream>>>(
      xb, wab, b_attn, 3 * C, C, Qb, Kb, Vb, nullptr);

  attn<<<dim3(8, BH), 512, 0, stream>>>(Qb, Kb, Vb, Yb);

  gemm_bt<0><<<dim3(C / 128, M / 128), 256, 0, stream>>>(
      Yb, wpb, b_proj, C, C, nullptr, nullptr, nullptr, out);
}